// Round 7
// baseline (429.740 us; speedup 1.0000x reference)
//
#include <hip/hip_runtime.h>
#include <hip/hip_fp16.h>

#define NN 50000
#define EE 800000
#define DD 96
#define GG 64
#define NH 12    // uint4 (8-half) chunks per 96-half row

#define FPSCALE 16777216.0f           // 2^24 fixed-point for weight sums
#define MASK44 ((1ULL << 44) - 1)
#define PSTR 8   // packed[] stride in u64 (64B per node)

typedef unsigned long long u64;

__device__ __forceinline__ void cvt8(uint4 v, float* f) {
    const __half2* h = (const __half2*)&v;
    #pragma unroll
    for (int k = 0; k < 4; ++k) {
        float2 t = __half22float2(h[k]);
        f[2 * k] = t.x; f[2 * k + 1] = t.y;
    }
}

__device__ __forceinline__ uint4 pack8(const float* f) {
    __half2 h0 = __floats2half2_rn(f[0], f[1]);
    __half2 h1 = __floats2half2_rn(f[2], f[3]);
    __half2 h2 = __floats2half2_rn(f[4], f[5]);
    __half2 h3 = __floats2half2_rn(f[6], f[7]);
    uint4 o;
    o.x = *(unsigned int*)&h0; o.y = *(unsigned int*)&h1;
    o.z = *(unsigned int*)&h2; o.w = *(unsigned int*)&h3;
    return o;
}

// ---------------- pre-pass: zero state + fp16 conversions ----------------

__global__ void k_pre(u64* packed, float* gsum, unsigned* sem, unsigned* done,
                      const float4* __restrict__ x, uint4* __restrict__ xh,
                      const float4* __restrict__ W1, uint4* __restrict__ w1h,
                      const float4* __restrict__ W3, uint4* __restrict__ w3h) {
    int i = blockIdx.x * 256 + threadIdx.x;
    if (i < NN) packed[(size_t)i * PSTR] = 0ULL;
    if (i < GG * DD) gsum[i] = 0.f;
    if (i < 256) sem[i] = 0u;
    if (i == 0) *done = 0u;
    if (i < 1152) {   // W1 -> fp16
        float4 f0 = W1[2 * i], f1 = W1[2 * i + 1];
        float f[8] = {f0.x, f0.y, f0.z, f0.w, f1.x, f1.y, f1.z, f1.w};
        w1h[i] = pack8(f);
    } else if (i < 2304) {   // W3 -> fp16
        int j = i - 1152;
        float4 f0 = W3[2 * j], f1 = W3[2 * j + 1];
        float f[8] = {f0.x, f0.y, f0.z, f0.w, f1.x, f1.y, f1.z, f1.w};
        w3h[j] = pack8(f);
    }
    if (i < NN * DD / 8) {   // x -> fp16
        float4 f0 = x[2 * i], f1 = x[2 * i + 1];
        float f[8] = {f0.x, f0.y, f0.z, f0.w, f1.x, f1.y, f1.z, f1.w};
        xh[i] = pack8(f);
    }
}

// ---------------- histogram (1 u64 atomic per edge) ----------------

__global__ void k_hist(const int* __restrict__ dst, const float* __restrict__ ew,
                       u64* packed, unsigned int* rank) {
    int e = blockIdx.x * 256 + threadIdx.x;
    if (e < EE) {
        u64 q = (u64)(ew[e] * FPSCALE + 0.5f);
        u64 old = atomicAdd(&packed[(size_t)dst[e] * PSTR], (1ULL << 44) | q);
        rank[e] = (unsigned int)(old >> 44);
    }
}

// ---------------- chained single-pass scan: dinv + row_ptr ----------------
// 196 blocks, always co-resident (196 << capacity). sem[b] = 0x80000000 | inclusive_prefix.

__global__ __launch_bounds__(256) void k_scan(const u64* __restrict__ packed,
                                              float* dinv, int* row_ptr, unsigned* sem) {
    __shared__ int s[256];
    __shared__ int sprefix;
    int b = blockIdx.x, tid = threadIdx.x;
    int i = b * 256 + tid;
    u64 p = (i < NN) ? packed[(size_t)i * PSTR] : 0ULL;
    if (i < NN) dinv[i] = rsqrtf(1.0f + (float)(p & MASK44) * (1.0f / FPSCALE));
    int v = (int)(p >> 44);
    s[tid] = v; __syncthreads();
    for (int off = 1; off < 256; off <<= 1) {
        int t = (tid >= off) ? s[tid - off] : 0;
        __syncthreads();
        s[tid] += t;
        __syncthreads();
    }
    int incl = s[tid];
    int total = s[255];
    if (tid == 0) {
        unsigned prev = 0;
        if (b > 0) {
            do { prev = atomicAdd(&sem[b - 1], 0u); __builtin_amdgcn_s_sleep(1); }
            while (!(prev & 0x80000000u));
            prev &= 0x7fffffffu;
        }
        atomicExch(&sem[b], 0x80000000u | (prev + (unsigned)total));
        sprefix = (int)prev;
    }
    __syncthreads();
    if (i < NN) row_ptr[i] = sprefix + incl - v;   // exclusive
    if (b == gridDim.x - 1 && tid == 255) row_ptr[NN] = EE;
}

// ---------------- scatter (no atomics) ----------------

__global__ void k_scatter(const int* __restrict__ src, const int* __restrict__ dst,
                          const float* __restrict__ ew, const float* __restrict__ dinv,
                          const int* __restrict__ row_ptr,
                          const unsigned int* __restrict__ rank, int2* csr) {
    int e = blockIdx.x * 256 + threadIdx.x;
    if (e < EE) {
        int s = src[e], d = dst[e];
        int p = row_ptr[d] + (int)rank[e];
        float w = dinv[s] * ew[e] * dinv[d];
        csr[p] = make_int2(s, __float_as_int(w));
    }
}

// ---------------- fused propagate + GEMM ----------------
// 192 threads = 16 nodes x 12 chunks. Gather phase fills Prow (LDS), then
// GEMM phase computes row @ W (W fp16 in LDS) overlapped across waves.
// L==1: out = relu(P@W1+b1) -> fp16 outH.  L==2: out = P@W3+b3 -> f32 outF; P -> P2.

template<int L>
__global__ __launch_bounds__(192) void k_prop_gemm(const uint4* __restrict__ Th,
                                                   const int2* __restrict__ csr,
                                                   const int* __restrict__ row_ptr,
                                                   const float* __restrict__ dinv,
                                                   const uint4* __restrict__ Wh,
                                                   const float* __restrict__ bias,
                                                   uint4* __restrict__ outH,
                                                   float* __restrict__ outF,
                                                   float* __restrict__ P2) {
    __shared__ uint4 sW[1152];          // 96x96 fp16 = 18 KB
    __shared__ float Prow[16][100];     // stride 100: float4-aligned, 2-way bank (free)
    int tid = threadIdx.x;
    #pragma unroll
    for (int i = 0; i < 6; ++i) sW[tid + 192 * i] = Wh[tid + 192 * i];

    int n = tid / 12, c = tid % 12;
    int node = blockIdx.x * 16 + n;     // grid is exactly NN/16 blocks
    float di = dinv[node];
    float self = di * di;
    float f[8], acc[8];
    cvt8(Th[node * NH + c], f);
    #pragma unroll
    for (int j = 0; j < 8; ++j) acc[j] = self * f[j];
    int e0 = row_ptr[node], e1 = row_ptr[node + 1];
    for (int e = e0; e < e1; ++e) {
        int2 sw = csr[e];
        float w = __int_as_float(sw.y);
        cvt8(Th[sw.x * NH + c], f);
        #pragma unroll
        for (int j = 0; j < 8; ++j) acc[j] = fmaf(w, f[j], acc[j]);
    }
    if (L == 2) {   // save P2 for the pool
        float4* o = (float4*)(P2 + (size_t)node * DD + c * 8);
        o[0] = make_float4(acc[0], acc[1], acc[2], acc[3]);
        o[1] = make_float4(acc[4], acc[5], acc[6], acc[7]);
    }
    #pragma unroll
    for (int j = 0; j < 8; ++j) Prow[n][c * 8 + j] = acc[j];
    __syncthreads();

    // GEMM: out[8] = bias + sum_k Prow[n][k] * W[k][8c..8c+8)
    float out[8];
    {
        float4 b0 = *(const float4*)(bias + c * 8);
        float4 b1 = *(const float4*)(bias + c * 8 + 4);
        out[0] = b0.x; out[1] = b0.y; out[2] = b0.z; out[3] = b0.w;
        out[4] = b1.x; out[5] = b1.y; out[6] = b1.z; out[7] = b1.w;
    }
    #pragma unroll 4
    for (int k = 0; k < DD; ++k) {
        float pr = Prow[n][k];
        cvt8(sW[k * 12 + c], f);
        #pragma unroll
        for (int j = 0; j < 8; ++j) out[j] = fmaf(pr, f[j], out[j]);
    }
    if (L == 1) {
        #pragma unroll
        for (int j = 0; j < 8; ++j) out[j] = fmaxf(out[j], 0.f);
        outH[node * NH + c] = pack8(out);
    } else {
        float4* o = (float4*)(outF + (size_t)node * DD + c * 8);
        o[0] = make_float4(out[0], out[1], out[2], out[3]);
        o[1] = make_float4(out[4], out[5], out[6], out[7]);
    }
}

// ---------------- pool: stage A (512 blocks) + last-block stage B ----------------

__global__ __launch_bounds__(384) void k_pool(const float* __restrict__ P2,
                                              const int* __restrict__ batch,
                                              const float* __restrict__ W4,
                                              const float* __restrict__ b4,
                                              float* __restrict__ outG,
                                              float* gsum, unsigned* done) {
    int b = blockIdx.x;
    int g = b >> 3, s = b & 7;
    int tid = threadIdx.x;
    int d = tid % 96, t = tid / 96;
    int lo = 0, hi = NN;
    while (lo < hi) { int m = (lo + hi) >> 1; if (batch[m] < g) lo = m + 1; else hi = m; }
    int start = lo;
    lo = 0; hi = NN;
    while (lo < hi) { int m = (lo + hi) >> 1; if (batch[m] < g + 1) lo = m + 1; else hi = m; }
    int end = lo;
    float acc = 0.f;
    for (int i = start + s * 4 + t; i < end; i += 32) acc += P2[(size_t)i * DD + d];
    __shared__ float red[384];
    red[tid] = acc;
    __syncthreads();
    if (tid < 96) {
        float v = red[tid] + red[tid + 96] + red[tid + 192] + red[tid + 288];
        atomicAdd(&gsum[g * 96 + tid], v);
    }
    __threadfence();
    __shared__ int last;
    __syncthreads();
    if (tid == 0) last = (atomicAdd(done, 1u) == (unsigned)(GG * 8 - 1)) ? 1 : 0;
    __syncthreads();
    if (!last) return;
    __threadfence();

    // stage B: outG = gsum @ W4 + cnt * b4   (one block)
    __shared__ float sg[GG * DD];       // 24 KB
    __shared__ int cnt[GG];
    for (int i = tid; i < GG * DD; i += 384) sg[i] = atomicAdd(&gsum[i], 0.f);
    if (tid < GG) {
        int gg = tid;
        int l = 0, h = NN;
        while (l < h) { int m = (l + h) >> 1; if (batch[m] < gg) l = m + 1; else h = m; }
        int st = l;
        l = 0; h = NN;
        while (l < h) { int m = (l + h) >> 1; if (batch[m] < gg + 1) l = m + 1; else h = m; }
        cnt[tid] = l - st;
    }
    __syncthreads();
    for (int i = tid; i < GG * DD; i += 384) {
        int gg = i / 96, dd = i % 96;
        float o = (float)cnt[gg] * b4[dd];
        #pragma unroll 8
        for (int k = 0; k < 96; ++k) o = fmaf(sg[gg * 96 + k], W4[k * 96 + dd], o);
        outG[i] = o;
    }
}

// ---------------- launch ----------------

extern "C" void kernel_launch(void* const* d_in, const int* in_sizes, int n_in,
                              void* d_out, int out_size, void* d_ws, size_t ws_size,
                              hipStream_t stream) {
    const float* x  = (const float*)d_in[0];
    const float* W1 = (const float*)d_in[1];
    const float* b1 = (const float*)d_in[2];
    const float* W3 = (const float*)d_in[3];
    const float* b3 = (const float*)d_in[4];
    const float* W4 = (const float*)d_in[5];
    const float* b4 = (const float*)d_in[6];
    const float* ew = (const float*)d_in[7];
    const int* ei   = (const int*)d_in[8];
    const int* src  = ei;
    const int* dst  = ei + EE;
    const int* batch = (const int*)d_in[9];

    float* out_embed = (float*)d_out;
    float* out_graph = out_embed + (size_t)NN * DD;

    char* w = (char*)d_ws;
    auto alloc = [&](size_t bytes) { char* p = w; w += (bytes + 255) & ~(size_t)255; return p; };
    u64* packed    = (u64*)  alloc((size_t)NN * 8 * PSTR);
    unsigned* rank = (unsigned*)alloc((size_t)EE * 4);
    float* dinv    = (float*)alloc((size_t)NN * 4);
    int*   row_ptr = (int*)  alloc((size_t)(NN + 1) * 4);
    unsigned* sem  = (unsigned*)alloc(256 * 4);
    unsigned* done = (unsigned*)alloc(256);
    float* gsum    = (float*)alloc((size_t)GG * DD * 4);
    int2*  csr     = (int2*) alloc((size_t)EE * 8);
    uint4* xh      = (uint4*)alloc((size_t)NN * DD * 2);   // fp16 x
    uint4* hh      = (uint4*)alloc((size_t)NN * DD * 2);   // fp16 h
    uint4* w1h     = (uint4*)alloc(1152 * 16);
    uint4* w3h     = (uint4*)alloc(1152 * 16);
    float* p2      = (float*)alloc((size_t)NN * DD * 4);

    int nbE = (EE + 255) / 256;       // 3125
    int nbP = (NN * DD / 8 + 255) / 256;

    k_pre<<<nbP, 256, 0, stream>>>(packed, gsum, sem, done,
                                   (const float4*)x, xh,
                                   (const float4*)W1, w1h,
                                   (const float4*)W3, w3h);
    k_hist<<<nbE, 256, 0, stream>>>(dst, ew, packed, rank);
    k_scan<<<(NN + 255) / 256, 256, 0, stream>>>(packed, dinv, row_ptr, sem);
    k_scatter<<<nbE, 256, 0, stream>>>(src, dst, ew, dinv, row_ptr, rank, csr);

    // h = relu((A_hat x) W1 + b1) [fp16]
    k_prop_gemm<1><<<NN / 16, 192, 0, stream>>>(xh, csr, row_ptr, dinv, w1h, b1,
                                                hh, nullptr, nullptr);
    // embed = (A_hat h) W3 + b3 ; P2 saved
    k_prop_gemm<2><<<NN / 16, 192, 0, stream>>>(hh, csr, row_ptr, dinv, w3h, b3,
                                                nullptr, out_embed, p2);
    // out_graph = pool(P2) @ W4 + cnt * b4
    k_pool<<<GG * 8, 384, 0, stream>>>(p2, batch, W4, b4, out_graph, gsum, done);
}

// Round 8
// 305.279 us; speedup vs baseline: 1.4077x; 1.4077x over previous
//
#include <hip/hip_runtime.h>
#include <hip/hip_fp16.h>

#define NN 50000
#define EE 800000
#define DD 96
#define GG 64
#define NC 24    // float4 chunks per 96-float row
#define NH 12    // uint4 (8-half) chunks per 96-half row

#define FPSCALE 16777216.0f           // 2^24 fixed-point for weight sums
#define MASK44 ((1ULL << 44) - 1)
#define NCPY 8   // histogram copies (blockIdx&7 ~ XCD id under round-robin dispatch)

typedef unsigned long long u64;

__device__ __forceinline__ uint4 pack8(const float* f) {
    __half2 h0 = __floats2half2_rn(f[0], f[1]);
    __half2 h1 = __floats2half2_rn(f[2], f[3]);
    __half2 h2 = __floats2half2_rn(f[4], f[5]);
    __half2 h3 = __floats2half2_rn(f[6], f[7]);
    uint4 o;
    o.x = *(unsigned int*)&h0; o.y = *(unsigned int*)&h1;
    o.z = *(unsigned int*)&h2; o.w = *(unsigned int*)&h3;
    return o;
}

__device__ __forceinline__ void cvt8(uint4 v, float* f) {
    const __half2* h = (const __half2*)&v;
    #pragma unroll
    for (int k = 0; k < 4; ++k) {
        float2 t = __half22float2(h[k]);
        f[2 * k] = t.x; f[2 * k + 1] = t.y;
    }
}

// ---------------- pre-pass: zero state + x -> fp16 ----------------

__global__ void k_pre(u64* histo, float* gsum, unsigned* done,
                      const float4* __restrict__ x, uint4* __restrict__ xh) {
    int i = blockIdx.x * 256 + threadIdx.x;
    if (i < NCPY * NN) histo[i] = 0ULL;
    if (i < GG * DD) gsum[i] = 0.f;
    if (i == 0) *done = 0u;
    if (i < NN * DD / 8) {
        float4 f0 = x[2 * i], f1 = x[2 * i + 1];
        float f[8] = {f0.x, f0.y, f0.z, f0.w, f1.x, f1.y, f1.z, f1.w};
        xh[i] = pack8(f);
    }
}

// ---------------- histogram: 1 u64 atomic per edge, 8 copies ----------------
// copy = blockIdx&7 tracks XCD under round-robin dispatch; goal is to keep
// each copy's lines in one XCD's L2. rank[e] = (copy<<24) | rank_in_copy.

__global__ void k_hist(const int* __restrict__ dst, const float* __restrict__ ew,
                       u64* histo, unsigned int* rank) {
    int e = blockIdx.x * 256 + threadIdx.x;
    int cpy = blockIdx.x & (NCPY - 1);
    if (e < EE) {
        u64 q = (u64)(ew[e] * FPSCALE + 0.5f);
        u64 old = atomicAdd(&histo[(size_t)cpy * NN + dst[e]], (1ULL << 44) | q);
        rank[e] = ((unsigned)cpy << 24) | (unsigned)(old >> 44);
    }
}

// ---------------- reduce 8 copies: dinv, per-copy offsets, block count sums ----------------

__global__ __launch_bounds__(256) void k_dinv_reduce(const u64* __restrict__ histo,
                                                     float* dinv, int* cnts,
                                                     unsigned* xoff, int* bsums) {
    __shared__ int s[256];
    int tid = threadIdx.x;
    int i = blockIdx.x * 256 + tid;
    int tot = 0;
    if (i < NN) {
        u64 wsum44 = 0;
        unsigned pre = 0;
        #pragma unroll
        for (int x = 0; x < NCPY; ++x) {
            u64 h = histo[(size_t)x * NN + i];
            wsum44 += h & MASK44;
            xoff[(size_t)i * NCPY + x] = pre;
            pre += (unsigned)(h >> 44);
        }
        tot = (int)pre;
        cnts[i] = tot;
        dinv[i] = rsqrtf(1.0f + (float)wsum44 * (1.0f / FPSCALE));
    }
    s[tid] = tot;
    __syncthreads();
    for (int off = 128; off > 0; off >>= 1) {
        if (tid < off) s[tid] += s[tid + off];
        __syncthreads();
    }
    if (tid == 0) bsums[blockIdx.x] = s[0];
}

__global__ void k_scan_bsums(int* bsums, int nb, int* row_ptr) {
    __shared__ int s[256];
    int tid = threadIdx.x;
    int v = (tid < nb) ? bsums[tid] : 0;
    s[tid] = v; __syncthreads();
    for (int off = 1; off < 256; off <<= 1) {
        int t = (tid >= off) ? s[tid - off] : 0;
        __syncthreads();
        s[tid] += t;
        __syncthreads();
    }
    if (tid < nb) bsums[tid] = s[tid] - v;   // exclusive
    if (tid == 0) row_ptr[NN] = EE;
}

__global__ void k_scan_counts(const int* __restrict__ cnts,
                              const int* __restrict__ bsums, int* row_ptr) {
    __shared__ int s[256];
    int tid = threadIdx.x;
    int i = blockIdx.x * 256 + tid;
    int v = (i < NN) ? cnts[i] : 0;
    s[tid] = v; __syncthreads();
    for (int off = 1; off < 256; off <<= 1) {
        int t = (tid >= off) ? s[tid - off] : 0;
        __syncthreads();
        s[tid] += t;
        __syncthreads();
    }
    if (i < NN) row_ptr[i] = bsums[blockIdx.x] + s[tid] - v;   // exclusive
}

// ---------------- scatter (no atomics) ----------------

__global__ void k_scatter(const int* __restrict__ src, const int* __restrict__ dst,
                          const float* __restrict__ ew, const float* __restrict__ dinv,
                          const int* __restrict__ row_ptr, const unsigned* __restrict__ xoff,
                          const unsigned int* __restrict__ rank, int2* csr) {
    int e = blockIdx.x * 256 + threadIdx.x;
    if (e < EE) {
        int s = src[e], d = dst[e];
        unsigned r = rank[e];
        int x = (int)(r >> 24);
        int p = row_ptr[d] + (int)xoff[(size_t)d * NCPY + x] + (int)(r & 0xFFFFFFu);
        float w = dinv[s] * ew[e] * dinv[d];
        csr[p] = make_int2(s, __float_as_int(w));
    }
}

// ---------------- propagation (CSR gather, fp16 rows): P = A_hat * T ----------------
// 192 threads = 16 nodes x 12 chunks of 8 halves. f32 accumulate, f32 output.

__global__ __launch_bounds__(192) void k_prop_h(const uint4* __restrict__ Th,
                                                const int2* __restrict__ csr,
                                                const int* __restrict__ row_ptr,
                                                const float* __restrict__ dinv,
                                                float* __restrict__ P) {
    int tid = threadIdx.x;
    int node = blockIdx.x * 16 + tid / 12;
    int c = tid % 12;
    if (node >= NN) return;
    float di = dinv[node];
    float self = di * di;
    float f[8], acc[8];
    cvt8(Th[node * NH + c], f);
    #pragma unroll
    for (int j = 0; j < 8; ++j) acc[j] = self * f[j];
    int e0 = row_ptr[node], e1 = row_ptr[node + 1];
    for (int e = e0; e < e1; ++e) {
        int2 sw = csr[e];
        float w = __int_as_float(sw.y);
        cvt8(Th[sw.x * NH + c], f);
        #pragma unroll
        for (int j = 0; j < 8; ++j) acc[j] = fmaf(w, f[j], acc[j]);
    }
    float4* o = (float4*)(P + (size_t)node * DD + c * 8);
    o[0] = make_float4(acc[0], acc[1], acc[2], acc[3]);
    o[1] = make_float4(acc[4], acc[5], acc[6], acc[7]);
}

// ---------------- GEMM: O = act(X @ W + b)  (W in LDS) ----------------
// 256 threads; each thread: 4 rows x 12 cols. Block covers 128 rows.
// MODE 0: relu, fp16 output. MODE 1: plain, f32 output.

__device__ __forceinline__ void fma4(float4& a, float s, const float4 w) {
    a.x = fmaf(s, w.x, a.x); a.y = fmaf(s, w.y, a.y);
    a.z = fmaf(s, w.z, a.z); a.w = fmaf(s, w.w, a.w);
}

template<int MODE>
__global__ __launch_bounds__(256) void k_gemm_bias(const float* __restrict__ X,
                                                   const float* __restrict__ W,
                                                   const float* __restrict__ bias,
                                                   float* __restrict__ O,
                                                   __half2* __restrict__ Oh) {
    __shared__ float sW[DD * DD];
    int tid = threadIdx.x;
    for (int i = tid; i < DD * DD / 4; i += 256)
        ((float4*)sW)[i] = ((const float4*)W)[i];
    __syncthreads();
    int cg = tid & 7, s = tid >> 3;
    int base = blockIdx.x * 128;
    const float4* bv = (const float4*)bias + cg * 3;
    const float4* xr0; const float4* xr1; const float4* xr2; const float4* xr3;
    {
        int r0 = base + s;        int c0 = r0 < NN ? r0 : NN - 1;
        int r1 = base + s + 32;   int c1 = r1 < NN ? r1 : NN - 1;
        int r2 = base + s + 64;   int c2 = r2 < NN ? r2 : NN - 1;
        int r3 = base + s + 96;   int c3 = r3 < NN ? r3 : NN - 1;
        xr0 = (const float4*)(X + (size_t)c0 * DD);
        xr1 = (const float4*)(X + (size_t)c1 * DD);
        xr2 = (const float4*)(X + (size_t)c2 * DD);
        xr3 = (const float4*)(X + (size_t)c3 * DD);
    }
    float4 acc[4][3];
    #pragma unroll
    for (int j = 0; j < 4; ++j) { acc[j][0] = bv[0]; acc[j][1] = bv[1]; acc[j][2] = bv[2]; }

    #pragma unroll 2
    for (int k4 = 0; k4 < NC; ++k4) {
        float4 xv0 = xr0[k4], xv1 = xr1[k4], xv2 = xr2[k4], xv3 = xr3[k4];
        #pragma unroll
        for (int kk = 0; kk < 4; ++kk) {
            const float4* wr = (const float4*)&sW[(k4 * 4 + kk) * DD + cg * 12];
            float4 w0 = wr[0], w1 = wr[1], w2 = wr[2];
            float s0 = kk == 0 ? xv0.x : kk == 1 ? xv0.y : kk == 2 ? xv0.z : xv0.w;
            float s1 = kk == 0 ? xv1.x : kk == 1 ? xv1.y : kk == 2 ? xv1.z : xv1.w;
            float s2 = kk == 0 ? xv2.x : kk == 1 ? xv2.y : kk == 2 ? xv2.z : xv2.w;
            float s3 = kk == 0 ? xv3.x : kk == 1 ? xv3.y : kk == 2 ? xv3.z : xv3.w;
            fma4(acc[0][0], s0, w0); fma4(acc[0][1], s0, w1); fma4(acc[0][2], s0, w2);
            fma4(acc[1][0], s1, w0); fma4(acc[1][1], s1, w1); fma4(acc[1][2], s1, w2);
            fma4(acc[2][0], s2, w0); fma4(acc[2][1], s2, w1); fma4(acc[2][2], s2, w2);
            fma4(acc[3][0], s3, w0); fma4(acc[3][1], s3, w1); fma4(acc[3][2], s3, w2);
        }
    }
    #pragma unroll
    for (int j = 0; j < 4; ++j) {
        int row = base + s + 32 * j;
        if (row >= NN) continue;
        float4 a0 = acc[j][0], a1 = acc[j][1], a2 = acc[j][2];
        if (MODE == 0) {
            a0.x = fmaxf(a0.x, 0.f); a0.y = fmaxf(a0.y, 0.f); a0.z = fmaxf(a0.z, 0.f); a0.w = fmaxf(a0.w, 0.f);
            a1.x = fmaxf(a1.x, 0.f); a1.y = fmaxf(a1.y, 0.f); a1.z = fmaxf(a1.z, 0.f); a1.w = fmaxf(a1.w, 0.f);
            a2.x = fmaxf(a2.x, 0.f); a2.y = fmaxf(a2.y, 0.f); a2.z = fmaxf(a2.z, 0.f); a2.w = fmaxf(a2.w, 0.f);
            __half2* o = Oh + ((size_t)row * DD + cg * 12) / 2;
            o[0] = __floats2half2_rn(a0.x, a0.y);
            o[1] = __floats2half2_rn(a0.z, a0.w);
            o[2] = __floats2half2_rn(a1.x, a1.y);
            o[3] = __floats2half2_rn(a1.z, a1.w);
            o[4] = __floats2half2_rn(a2.x, a2.y);
            o[5] = __floats2half2_rn(a2.z, a2.w);
        } else {
            float4* o = (float4*)(O + (size_t)row * DD + cg * 12);
            o[0] = a0; o[1] = a1; o[2] = a2;
        }
    }
}

// ---------------- pool: stage A (512 blocks) + last-block stage B ----------------

__global__ __launch_bounds__(384) void k_pool(const float* __restrict__ P2,
                                              const int* __restrict__ batch,
                                              const float* __restrict__ W4,
                                              const float* __restrict__ b4,
                                              float* __restrict__ outG,
                                              float* gsum, unsigned* done) {
    int b = blockIdx.x;
    int g = b >> 3, s = b & 7;
    int tid = threadIdx.x;
    int d = tid % 96, t = tid / 96;
    int lo = 0, hi = NN;
    while (lo < hi) { int m = (lo + hi) >> 1; if (batch[m] < g) lo = m + 1; else hi = m; }
    int start = lo;
    lo = 0; hi = NN;
    while (lo < hi) { int m = (lo + hi) >> 1; if (batch[m] < g + 1) lo = m + 1; else hi = m; }
    int end = lo;
    float acc = 0.f;
    for (int i = start + s * 4 + t; i < end; i += 32) acc += P2[(size_t)i * DD + d];
    __shared__ float red[384];
    red[tid] = acc;
    __syncthreads();
    if (tid < 96) {
        float v = red[tid] + red[tid + 96] + red[tid + 192] + red[tid + 288];
        atomicAdd(&gsum[g * 96 + tid], v);
    }
    __threadfence();
    __shared__ int last;
    __syncthreads();
    if (tid == 0) last = (atomicAdd(done, 1u) == (unsigned)(GG * 8 - 1)) ? 1 : 0;
    __syncthreads();
    if (!last) return;
    __threadfence();

    // stage B: outG = gsum @ W4 + cnt * b4   (one block)
    __shared__ float sg[GG * DD];       // 24 KB
    __shared__ int cnt[GG];
    for (int i = tid; i < GG * DD; i += 384) sg[i] = atomicAdd(&gsum[i], 0.f);
    if (tid < GG) {
        int gg = tid;
        int l = 0, h = NN;
        while (l < h) { int m = (l + h) >> 1; if (batch[m] < gg) l = m + 1; else h = m; }
        int st = l;
        l = 0; h = NN;
        while (l < h) { int m = (l + h) >> 1; if (batch[m] < gg + 1) l = m + 1; else h = m; }
        cnt[tid] = l - st;
    }
    __syncthreads();
    for (int i = tid; i < GG * DD; i += 384) {
        int gg = i / 96, dd = i % 96;
        float o = (float)cnt[gg] * b4[dd];
        #pragma unroll 8
        for (int k = 0; k < 96; ++k) o = fmaf(sg[gg * 96 + k], W4[k * 96 + dd], o);
        outG[i] = o;
    }
}

// ---------------- launch ----------------

extern "C" void kernel_launch(void* const* d_in, const int* in_sizes, int n_in,
                              void* d_out, int out_size, void* d_ws, size_t ws_size,
                              hipStream_t stream) {
    const float* x  = (const float*)d_in[0];
    const float* W1 = (const float*)d_in[1];
    const float* b1 = (const float*)d_in[2];
    const float* W3 = (const float*)d_in[3];
    const float* b3 = (const float*)d_in[4];
    const float* W4 = (const float*)d_in[5];
    const float* b4 = (const float*)d_in[6];
    const float* ew = (const float*)d_in[7];
    const int* ei   = (const int*)d_in[8];
    const int* src  = ei;
    const int* dst  = ei + EE;
    const int* batch = (const int*)d_in[9];

    float* out_embed = (float*)d_out;
    float* out_graph = out_embed + (size_t)NN * DD;

    char* w = (char*)d_ws;
    auto alloc = [&](size_t bytes) { char* p = w; w += (bytes + 255) & ~(size_t)255; return p; };
    u64* histo     = (u64*)  alloc((size_t)NCPY * NN * 8);
    unsigned* rank = (unsigned*)alloc((size_t)EE * 4);
    float* dinv    = (float*)alloc((size_t)NN * 4);
    int*   cnts    = (int*)  alloc((size_t)NN * 4);
    unsigned* xoff = (unsigned*)alloc((size_t)NN * NCPY * 4);
    int*   row_ptr = (int*)  alloc((size_t)(NN + 1) * 4);
    int*   bsums   = (int*)  alloc(256 * 4);
    unsigned* done = (unsigned*)alloc(256);
    float* gsum    = (float*)alloc((size_t)GG * DD * 4);
    int2*  csr     = (int2*) alloc((size_t)EE * 8);
    uint4* xh      = (uint4*)alloc((size_t)NN * DD * 2);   // fp16 x
    uint4* hh      = (uint4*)alloc((size_t)NN * DD * 2);   // fp16 h
    float* p1      = (float*)alloc((size_t)NN * DD * 4);   // A_hat @ x, reused as P2
    float* p2 = p1;   // p1 dead after first gemm; prop(h) writes here

    int nbN = (NN + 255) / 256;       // 196
    int nbE = (EE + 255) / 256;       // 3125
    int nbP = (NN * DD / 8 + 255) / 256;

    k_pre<<<nbP, 256, 0, stream>>>(histo, gsum, done, (const float4*)x, xh);
    k_hist<<<nbE, 256, 0, stream>>>(dst, ew, histo, rank);
    k_dinv_reduce<<<nbN, 256, 0, stream>>>(histo, dinv, cnts, xoff, bsums);
    k_scan_bsums<<<1, 256, 0, stream>>>(bsums, nbN, row_ptr);
    k_scan_counts<<<nbN, 256, 0, stream>>>(cnts, bsums, row_ptr);
    k_scatter<<<nbE, 256, 0, stream>>>(src, dst, ew, dinv, row_ptr, xoff, rank, csr);

    // P1 = A_hat @ x ; h = relu(P1 @ W1 + b1) [fp16]
    k_prop_h<<<(NN + 15) / 16, 192, 0, stream>>>(xh, csr, row_ptr, dinv, p1);
    k_gemm_bias<0><<<(NN + 127) / 128, 256, 0, stream>>>(p1, W1, b1, nullptr, (__half2*)hh);
    // P2 = A_hat @ h ; embed = P2 @ W3 + b3
    k_prop_h<<<(NN + 15) / 16, 192, 0, stream>>>(hh, csr, row_ptr, dinv, p2);
    k_gemm_bias<1><<<(NN + 127) / 128, 256, 0, stream>>>(p2, W3, b3, out_embed, nullptr);
    // out_graph = pool(P2) @ W4 + cnt * b4
    k_pool<<<GG * 8, 384, 0, stream>>>(p2, batch, W4, b4, out_graph, gsum, done);
}

// Round 9
// 215.377 us; speedup vs baseline: 1.9953x; 1.4174x over previous
//
#include <hip/hip_runtime.h>
#include <hip/hip_fp16.h>

#define NN 50000
#define EE 800000
#define DD 96
#define GG 64
#define NC 24    // float4 chunks per 96-float row
#define NH 12    // uint4 (8-half) chunks per 96-half row

#define FPSCALE 16777216.0f           // 2^24 fixed-point for weight sums
#define MASK44 ((1ULL << 44) - 1)
#define NCPY 8   // histogram copies (blockIdx&7 ~ XCD id under round-robin dispatch)

typedef unsigned long long u64;

__device__ __forceinline__ uint4 pack8(const float* f) {
    __half2 h0 = __floats2half2_rn(f[0], f[1]);
    __half2 h1 = __floats2half2_rn(f[2], f[3]);
    __half2 h2 = __floats2half2_rn(f[4], f[5]);
    __half2 h3 = __floats2half2_rn(f[6], f[7]);
    uint4 o;
    o.x = *(unsigned int*)&h0; o.y = *(unsigned int*)&h1;
    o.z = *(unsigned int*)&h2; o.w = *(unsigned int*)&h3;
    return o;
}

__device__ __forceinline__ void cvt8(uint4 v, float* f) {
    const __half2* h = (const __half2*)&v;
    #pragma unroll
    for (int k = 0; k < 4; ++k) {
        float2 t = __half22float2(h[k]);
        f[2 * k] = t.x; f[2 * k + 1] = t.y;
    }
}

// ---------------- pre-pass: zero state + x -> fp16 ----------------

__global__ void k_pre(u64* histo, float* gsum,
                      const float4* __restrict__ x, uint4* __restrict__ xh) {
    int i = blockIdx.x * 256 + threadIdx.x;
    if (i < NCPY * NN) histo[i] = 0ULL;
    if (i < GG * DD) gsum[i] = 0.f;
    if (i < NN * DD / 8) {
        float4 f0 = x[2 * i], f1 = x[2 * i + 1];
        float f[8] = {f0.x, f0.y, f0.z, f0.w, f1.x, f1.y, f1.z, f1.w};
        xh[i] = pack8(f);
    }
}

// ---------------- histogram: 1 u64 atomic per edge, 8 copies ----------------

__global__ void k_hist(const int* __restrict__ dst, const float* __restrict__ ew,
                       u64* histo, unsigned int* rank) {
    int e = blockIdx.x * 256 + threadIdx.x;
    int cpy = blockIdx.x & (NCPY - 1);
    if (e < EE) {
        u64 q = (u64)(ew[e] * FPSCALE + 0.5f);
        u64 old = atomicAdd(&histo[(size_t)cpy * NN + dst[e]], (1ULL << 44) | q);
        rank[e] = ((unsigned)cpy << 24) | (unsigned)(old >> 44);
    }
}

// ---------------- reduce 8 copies: dinv, per-copy offsets, block count sums ----------------

__global__ __launch_bounds__(256) void k_dinv_reduce(const u64* __restrict__ histo,
                                                     float* dinv, int* cnts,
                                                     unsigned* xoff, int* bsums) {
    __shared__ int s[256];
    int tid = threadIdx.x;
    int i = blockIdx.x * 256 + tid;
    int tot = 0;
    if (i < NN) {
        u64 wsum44 = 0;
        unsigned pre = 0;
        #pragma unroll
        for (int x = 0; x < NCPY; ++x) {
            u64 h = histo[(size_t)x * NN + i];
            wsum44 += h & MASK44;
            xoff[(size_t)i * NCPY + x] = pre;
            pre += (unsigned)(h >> 44);
        }
        tot = (int)pre;
        cnts[i] = tot;
        dinv[i] = rsqrtf(1.0f + (float)wsum44 * (1.0f / FPSCALE));
    }
    s[tid] = tot;
    __syncthreads();
    for (int off = 128; off > 0; off >>= 1) {
        if (tid < off) s[tid] += s[tid + off];
        __syncthreads();
    }
    if (tid == 0) bsums[blockIdx.x] = s[0];
}

__global__ void k_scan_bsums(int* bsums, int nb, int* row_ptr) {
    __shared__ int s[256];
    int tid = threadIdx.x;
    int v = (tid < nb) ? bsums[tid] : 0;
    s[tid] = v; __syncthreads();
    for (int off = 1; off < 256; off <<= 1) {
        int t = (tid >= off) ? s[tid - off] : 0;
        __syncthreads();
        s[tid] += t;
        __syncthreads();
    }
    if (tid < nb) bsums[tid] = s[tid] - v;   // exclusive
    if (tid == 0) row_ptr[NN] = EE;
}

__global__ void k_scan_counts(const int* __restrict__ cnts,
                              const int* __restrict__ bsums, int* row_ptr) {
    __shared__ int s[256];
    int tid = threadIdx.x;
    int i = blockIdx.x * 256 + tid;
    int v = (i < NN) ? cnts[i] : 0;
    s[tid] = v; __syncthreads();
    for (int off = 1; off < 256; off <<= 1) {
        int t = (tid >= off) ? s[tid - off] : 0;
        __syncthreads();
        s[tid] += t;
        __syncthreads();
    }
    if (i < NN) row_ptr[i] = bsums[blockIdx.x] + s[tid] - v;   // exclusive
}

// ---------------- scatter (no atomics) ----------------

__global__ void k_scatter(const int* __restrict__ src, const int* __restrict__ dst,
                          const float* __restrict__ ew, const float* __restrict__ dinv,
                          const int* __restrict__ row_ptr, const unsigned* __restrict__ xoff,
                          const unsigned int* __restrict__ rank, int2* csr) {
    int e = blockIdx.x * 256 + threadIdx.x;
    if (e < EE) {
        int s = src[e], d = dst[e];
        unsigned r = rank[e];
        int x = (int)(r >> 24);
        int p = row_ptr[d] + (int)xoff[(size_t)d * NCPY + x] + (int)(r & 0xFFFFFFu);
        float w = dinv[s] * ew[e] * dinv[d];
        csr[p] = make_int2(s, __float_as_int(w));
    }
}

// ---------------- propagation (CSR gather, fp16 rows): P = A_hat * T ----------------

__global__ __launch_bounds__(192) void k_prop_h(const uint4* __restrict__ Th,
                                                const int2* __restrict__ csr,
                                                const int* __restrict__ row_ptr,
                                                const float* __restrict__ dinv,
                                                float* __restrict__ P) {
    int tid = threadIdx.x;
    int node = blockIdx.x * 16 + tid / 12;
    int c = tid % 12;
    if (node >= NN) return;
    float di = dinv[node];
    float self = di * di;
    float f[8], acc[8];
    cvt8(Th[node * NH + c], f);
    #pragma unroll
    for (int j = 0; j < 8; ++j) acc[j] = self * f[j];
    int e0 = row_ptr[node], e1 = row_ptr[node + 1];
    for (int e = e0; e < e1; ++e) {
        int2 sw = csr[e];
        float w = __int_as_float(sw.y);
        cvt8(Th[sw.x * NH + c], f);
        #pragma unroll
        for (int j = 0; j < 8; ++j) acc[j] = fmaf(w, f[j], acc[j]);
    }
    float4* o = (float4*)(P + (size_t)node * DD + c * 8);
    o[0] = make_float4(acc[0], acc[1], acc[2], acc[3]);
    o[1] = make_float4(acc[4], acc[5], acc[6], acc[7]);
}

// ---------------- GEMM: O = act(X @ W + b)  (W in LDS) ----------------

__device__ __forceinline__ void fma4(float4& a, float s, const float4 w) {
    a.x = fmaf(s, w.x, a.x); a.y = fmaf(s, w.y, a.y);
    a.z = fmaf(s, w.z, a.z); a.w = fmaf(s, w.w, a.w);
}

template<int MODE>
__global__ __launch_bounds__(256) void k_gemm_bias(const float* __restrict__ X,
                                                   const float* __restrict__ W,
                                                   const float* __restrict__ bias,
                                                   float* __restrict__ O,
                                                   __half2* __restrict__ Oh) {
    __shared__ float sW[DD * DD];
    int tid = threadIdx.x;
    for (int i = tid; i < DD * DD / 4; i += 256)
        ((float4*)sW)[i] = ((const float4*)W)[i];
    __syncthreads();
    int cg = tid & 7, s = tid >> 3;
    int base = blockIdx.x * 128;
    const float4* bv = (const float4*)bias + cg * 3;
    const float4* xr0; const float4* xr1; const float4* xr2; const float4* xr3;
    {
        int r0 = base + s;        int c0 = r0 < NN ? r0 : NN - 1;
        int r1 = base + s + 32;   int c1 = r1 < NN ? r1 : NN - 1;
        int r2 = base + s + 64;   int c2 = r2 < NN ? r2 : NN - 1;
        int r3 = base + s + 96;   int c3 = r3 < NN ? r3 : NN - 1;
        xr0 = (const float4*)(X + (size_t)c0 * DD);
        xr1 = (const float4*)(X + (size_t)c1 * DD);
        xr2 = (const float4*)(X + (size_t)c2 * DD);
        xr3 = (const float4*)(X + (size_t)c3 * DD);
    }
    float4 acc[4][3];
    #pragma unroll
    for (int j = 0; j < 4; ++j) { acc[j][0] = bv[0]; acc[j][1] = bv[1]; acc[j][2] = bv[2]; }

    #pragma unroll 2
    for (int k4 = 0; k4 < NC; ++k4) {
        float4 xv0 = xr0[k4], xv1 = xr1[k4], xv2 = xr2[k4], xv3 = xr3[k4];
        #pragma unroll
        for (int kk = 0; kk < 4; ++kk) {
            const float4* wr = (const float4*)&sW[(k4 * 4 + kk) * DD + cg * 12];
            float4 w0 = wr[0], w1 = wr[1], w2 = wr[2];
            float s0 = kk == 0 ? xv0.x : kk == 1 ? xv0.y : kk == 2 ? xv0.z : xv0.w;
            float s1 = kk == 0 ? xv1.x : kk == 1 ? xv1.y : kk == 2 ? xv1.z : xv1.w;
            float s2 = kk == 0 ? xv2.x : kk == 1 ? xv2.y : kk == 2 ? xv2.z : xv2.w;
            float s3 = kk == 0 ? xv3.x : kk == 1 ? xv3.y : kk == 2 ? xv3.z : xv3.w;
            fma4(acc[0][0], s0, w0); fma4(acc[0][1], s0, w1); fma4(acc[0][2], s0, w2);
            fma4(acc[1][0], s1, w0); fma4(acc[1][1], s1, w1); fma4(acc[1][2], s1, w2);
            fma4(acc[2][0], s2, w0); fma4(acc[2][1], s2, w1); fma4(acc[2][2], s2, w2);
            fma4(acc[3][0], s3, w0); fma4(acc[3][1], s3, w1); fma4(acc[3][2], s3, w2);
        }
    }
    #pragma unroll
    for (int j = 0; j < 4; ++j) {
        int row = base + s + 32 * j;
        if (row >= NN) continue;
        float4 a0 = acc[j][0], a1 = acc[j][1], a2 = acc[j][2];
        if (MODE == 0) {
            a0.x = fmaxf(a0.x, 0.f); a0.y = fmaxf(a0.y, 0.f); a0.z = fmaxf(a0.z, 0.f); a0.w = fmaxf(a0.w, 0.f);
            a1.x = fmaxf(a1.x, 0.f); a1.y = fmaxf(a1.y, 0.f); a1.z = fmaxf(a1.z, 0.f); a1.w = fmaxf(a1.w, 0.f);
            a2.x = fmaxf(a2.x, 0.f); a2.y = fmaxf(a2.y, 0.f); a2.z = fmaxf(a2.z, 0.f); a2.w = fmaxf(a2.w, 0.f);
            __half2* o = Oh + ((size_t)row * DD + cg * 12) / 2;
            o[0] = __floats2half2_rn(a0.x, a0.y);
            o[1] = __floats2half2_rn(a0.z, a0.w);
            o[2] = __floats2half2_rn(a1.x, a1.y);
            o[3] = __floats2half2_rn(a1.z, a1.w);
            o[4] = __floats2half2_rn(a2.x, a2.y);
            o[5] = __floats2half2_rn(a2.z, a2.w);
        } else {
            float4* o = (float4*)(O + (size_t)row * DD + cg * 12);
            o[0] = a0; o[1] = a1; o[2] = a2;
        }
    }
}

// ---------------- pool stage A: per-graph striped partial sums ----------------

__global__ __launch_bounds__(384) void k_pool_a(const float* __restrict__ P2,
                                                const int* __restrict__ batch,
                                                float* __restrict__ gsum) {
    int b = blockIdx.x;
    int g = b >> 3, s = b & 7;
    int tid = threadIdx.x;
    int d = tid % 96, t = tid / 96;
    int lo = 0, hi = NN;
    while (lo < hi) { int m = (lo + hi) >> 1; if (batch[m] < g) lo = m + 1; else hi = m; }
    int start = lo;
    lo = 0; hi = NN;
    while (lo < hi) { int m = (lo + hi) >> 1; if (batch[m] < g + 1) lo = m + 1; else hi = m; }
    int end = lo;
    float acc = 0.f;
    for (int i = start + s * 4 + t; i < end; i += 32) acc += P2[(size_t)i * DD + d];
    __shared__ float red[384];
    red[tid] = acc;
    __syncthreads();
    if (tid < 96) {
        float v = red[tid] + red[tid + 96] + red[tid + 192] + red[tid + 288];
        atomicAdd(&gsum[g * 96 + tid], v);
    }
}

// ---------------- pool stage B: outG = gsum @ W4 + cnt * b4 ----------------

__global__ __launch_bounds__(96) void k_pool_b(const float* __restrict__ gsum,
                                               const int* __restrict__ batch,
                                               const float* __restrict__ W4,
                                               const float* __restrict__ b4,
                                               float* __restrict__ outG) {
    int g = blockIdx.x, d = threadIdx.x;
    __shared__ float srow[96];
    srow[d] = gsum[g * 96 + d];
    int lo = 0, hi = NN;
    while (lo < hi) { int m = (lo + hi) >> 1; if (batch[m] < g) lo = m + 1; else hi = m; }
    int start = lo;
    lo = 0; hi = NN;
    while (lo < hi) { int m = (lo + hi) >> 1; if (batch[m] < g + 1) lo = m + 1; else hi = m; }
    int end = lo;
    __syncthreads();
    float o = (float)(end - start) * b4[d];
    #pragma unroll 8
    for (int k = 0; k < 96; ++k) o = fmaf(srow[k], W4[k * 96 + d], o);
    outG[g * 96 + d] = o;
}

// ---------------- launch ----------------

extern "C" void kernel_launch(void* const* d_in, const int* in_sizes, int n_in,
                              void* d_out, int out_size, void* d_ws, size_t ws_size,
                              hipStream_t stream) {
    const float* x  = (const float*)d_in[0];
    const float* W1 = (const float*)d_in[1];
    const float* b1 = (const float*)d_in[2];
    const float* W3 = (const float*)d_in[3];
    const float* b3 = (const float*)d_in[4];
    const float* W4 = (const float*)d_in[5];
    const float* b4 = (const float*)d_in[6];
    const float* ew = (const float*)d_in[7];
    const int* ei   = (const int*)d_in[8];
    const int* src  = ei;
    const int* dst  = ei + EE;
    const int* batch = (const int*)d_in[9];

    float* out_embed = (float*)d_out;
    float* out_graph = out_embed + (size_t)NN * DD;

    char* w = (char*)d_ws;
    auto alloc = [&](size_t bytes) { char* p = w; w += (bytes + 255) & ~(size_t)255; return p; };
    u64* histo     = (u64*)  alloc((size_t)NCPY * NN * 8);
    unsigned* rank = (unsigned*)alloc((size_t)EE * 4);
    float* dinv    = (float*)alloc((size_t)NN * 4);
    int*   cnts    = (int*)  alloc((size_t)NN * 4);
    unsigned* xoff = (unsigned*)alloc((size_t)NN * NCPY * 4);
    int*   row_ptr = (int*)  alloc((size_t)(NN + 1) * 4);
    int*   bsums   = (int*)  alloc(256 * 4);
    float* gsum    = (float*)alloc((size_t)GG * DD * 4);
    int2*  csr     = (int2*) alloc((size_t)EE * 8);
    uint4* xh      = (uint4*)alloc((size_t)NN * DD * 2);   // fp16 x
    uint4* hh      = (uint4*)alloc((size_t)NN * DD * 2);   // fp16 h
    float* p1      = (float*)alloc((size_t)NN * DD * 4);   // A_hat @ x, reused as P2
    float* p2 = p1;   // p1 dead after first gemm; prop(h) writes here

    int nbN = (NN + 255) / 256;       // 196
    int nbE = (EE + 255) / 256;       // 3125
    int nbP = (NN * DD / 8 + 255) / 256;

    k_pre<<<nbP, 256, 0, stream>>>(histo, gsum, (const float4*)x, xh);
    k_hist<<<nbE, 256, 0, stream>>>(dst, ew, histo, rank);
    k_dinv_reduce<<<nbN, 256, 0, stream>>>(histo, dinv, cnts, xoff, bsums);
    k_scan_bsums<<<1, 256, 0, stream>>>(bsums, nbN, row_ptr);
    k_scan_counts<<<nbN, 256, 0, stream>>>(cnts, bsums, row_ptr);
    k_scatter<<<nbE, 256, 0, stream>>>(src, dst, ew, dinv, row_ptr, xoff, rank, csr);

    // P1 = A_hat @ x ; h = relu(P1 @ W1 + b1) [fp16]
    k_prop_h<<<(NN + 15) / 16, 192, 0, stream>>>(xh, csr, row_ptr, dinv, p1);
    k_gemm_bias<0><<<(NN + 127) / 128, 256, 0, stream>>>(p1, W1, b1, nullptr, (__half2*)hh);
    // P2 = A_hat @ h ; embed = P2 @ W3 + b3
    k_prop_h<<<(NN + 15) / 16, 192, 0, stream>>>(hh, csr, row_ptr, dinv, p2);
    k_gemm_bias<1><<<(NN + 127) / 128, 256, 0, stream>>>(p2, W3, b3, out_embed, nullptr);
    // out_graph = pool(P2) @ W4 + cnt * b4
    k_pool_a<<<GG * 8, 384, 0, stream>>>(p2, batch, gsum);
    k_pool_b<<<GG, 96, 0, stream>>>(gsum, batch, W4, b4, out_graph);
}

// Round 10
// 212.120 us; speedup vs baseline: 2.0259x; 1.0154x over previous
//
#include <hip/hip_runtime.h>
#include <hip/hip_fp16.h>

#define NN 50000
#define EE 800000
#define DD 96
#define GG 64
#define NH 12    // uint4 (8-half) chunks per 96-half row

#define FPSCALE 16777216.0f           // 2^24 fixed-point for weight sums
#define MASK44 ((1ULL << 44) - 1)
#define NCPY 8   // histogram copies
#define NBG ((NN + 127) / 128)        // 391 gemm blocks in k_tail

typedef unsigned long long u64;

__device__ __forceinline__ uint4 pack8(const float* f) {
    __half2 h0 = __floats2half2_rn(f[0], f[1]);
    __half2 h1 = __floats2half2_rn(f[2], f[3]);
    __half2 h2 = __floats2half2_rn(f[4], f[5]);
    __half2 h3 = __floats2half2_rn(f[6], f[7]);
    uint4 o;
    o.x = *(unsigned int*)&h0; o.y = *(unsigned int*)&h1;
    o.z = *(unsigned int*)&h2; o.w = *(unsigned int*)&h3;
    return o;
}

__device__ __forceinline__ void cvt8(uint4 v, float* f) {
    const __half2* h = (const __half2*)&v;
    #pragma unroll
    for (int k = 0; k < 4; ++k) {
        float2 t = __half22float2(h[k]);
        f[2 * k] = t.x; f[2 * k + 1] = t.y;
    }
}

// ---------------- pre-pass: zero state + x -> fp16 ----------------

__global__ void k_pre(u64* histo, float* gsum,
                      const float4* __restrict__ x, uint4* __restrict__ xh) {
    int i = blockIdx.x * 256 + threadIdx.x;
    if (i < NCPY * NN) histo[i] = 0ULL;
    if (i < GG * DD) gsum[i] = 0.f;
    if (i < NN * DD / 8) {
        float4 f0 = x[2 * i], f1 = x[2 * i + 1];
        float f[8] = {f0.x, f0.y, f0.z, f0.w, f1.x, f1.y, f1.z, f1.w};
        xh[i] = pack8(f);
    }
}

// ---------------- histogram: 1 u64 atomic per edge, 8 copies ----------------

__global__ void k_hist(const int* __restrict__ dst, const float* __restrict__ ew,
                       u64* histo, unsigned int* rank) {
    int e = blockIdx.x * 256 + threadIdx.x;
    int cpy = blockIdx.x & (NCPY - 1);
    if (e < EE) {
        u64 q = (u64)(ew[e] * FPSCALE + 0.5f);
        u64 old = atomicAdd(&histo[(size_t)cpy * NN + dst[e]], (1ULL << 44) | q);
        rank[e] = ((unsigned)cpy << 24) | (unsigned)(old >> 44);
    }
}

// ---------------- reduce 8 copies: dinv, per-copy offsets, block count sums ----------------

__global__ __launch_bounds__(256) void k_dinv_reduce(const u64* __restrict__ histo,
                                                     float* dinv, int* cnts,
                                                     unsigned* xoff, int* bsums) {
    __shared__ int s[256];
    int tid = threadIdx.x;
    int i = blockIdx.x * 256 + tid;
    int tot = 0;
    if (i < NN) {
        u64 wsum44 = 0;
        unsigned pre = 0;
        #pragma unroll
        for (int x = 0; x < NCPY; ++x) {
            u64 h = histo[(size_t)x * NN + i];
            wsum44 += h & MASK44;
            xoff[(size_t)i * NCPY + x] = pre;
            pre += (unsigned)(h >> 44);
        }
        tot = (int)pre;
        cnts[i] = tot;
        dinv[i] = rsqrtf(1.0f + (float)wsum44 * (1.0f / FPSCALE));
    }
    s[tid] = tot;
    __syncthreads();
    for (int off = 128; off > 0; off >>= 1) {
        if (tid < off) s[tid] += s[tid + off];
        __syncthreads();
    }
    if (tid == 0) bsums[blockIdx.x] = s[0];
}

// ---------------- merged scan: every block self-scans bsums, then local scan ----------------

__global__ __launch_bounds__(256) void k_scan2(const int* __restrict__ cnts,
                                               const int* __restrict__ bsums,
                                               int nb, int* row_ptr) {
    __shared__ int s[256];
    int tid = threadIdx.x;
    // scan block sums (all blocks redundantly; 196 ints)
    int bv = (tid < nb) ? bsums[tid] : 0;
    s[tid] = bv; __syncthreads();
    for (int off = 1; off < 256; off <<= 1) {
        int t = (tid >= off) ? s[tid - off] : 0;
        __syncthreads();
        s[tid] += t;
        __syncthreads();
    }
    int pb = (blockIdx.x > 0) ? s[blockIdx.x - 1] : 0;   // exclusive prefix for this block
    __syncthreads();
    // local scan of this block's counts
    int i = blockIdx.x * 256 + tid;
    int v = (i < NN) ? cnts[i] : 0;
    s[tid] = v; __syncthreads();
    for (int off = 1; off < 256; off <<= 1) {
        int t = (tid >= off) ? s[tid - off] : 0;
        __syncthreads();
        s[tid] += t;
        __syncthreads();
    }
    if (i < NN) row_ptr[i] = pb + s[tid] - v;   // exclusive
    if (blockIdx.x == gridDim.x - 1 && tid == 255) row_ptr[NN] = EE;
}

// ---------------- scatter (no atomics) ----------------

__global__ void k_scatter(const int* __restrict__ src, const int* __restrict__ dst,
                          const float* __restrict__ ew, const float* __restrict__ dinv,
                          const int* __restrict__ row_ptr, const unsigned* __restrict__ xoff,
                          const unsigned int* __restrict__ rank, int2* csr) {
    int e = blockIdx.x * 256 + threadIdx.x;
    if (e < EE) {
        int s = src[e], d = dst[e];
        unsigned r = rank[e];
        int x = (int)(r >> 24);
        int p = row_ptr[d] + (int)xoff[(size_t)d * NCPY + x] + (int)(r & 0xFFFFFFu);
        float w = dinv[s] * ew[e] * dinv[d];
        csr[p] = make_int2(s, __float_as_int(w));
    }
}

// ---------------- propagation (CSR gather, fp16 in AND out) ----------------
// 192 threads = 16 nodes x 12 chunks of 8 halves. f32 accumulate.

__global__ __launch_bounds__(192) void k_prop_h(const uint4* __restrict__ Th,
                                                const int2* __restrict__ csr,
                                                const int* __restrict__ row_ptr,
                                                const float* __restrict__ dinv,
                                                uint4* __restrict__ Ph) {
    int tid = threadIdx.x;
    int node = blockIdx.x * 16 + tid / 12;
    int c = tid % 12;
    float di = dinv[node];
    float self = di * di;
    float f[8], acc[8];
    cvt8(Th[node * NH + c], f);
    #pragma unroll
    for (int j = 0; j < 8; ++j) acc[j] = self * f[j];
    int e0 = row_ptr[node], e1 = row_ptr[node + 1];
    for (int e = e0; e < e1; ++e) {
        int2 sw = csr[e];
        float w = __int_as_float(sw.y);
        cvt8(Th[sw.x * NH + c], f);
        #pragma unroll
        for (int j = 0; j < 8; ++j) acc[j] = fmaf(w, f[j], acc[j]);
    }
    Ph[node * NH + c] = pack8(acc);
}

// ---------------- GEMM layer 1: hh = relu(Ph @ W1 + b1), fp16 out ----------------
// 256 threads; 4 rows x 12 cols per thread; A fp16, W f32 in LDS.

__device__ __forceinline__ void fma4(float4& a, float s, const float4 w) {
    a.x = fmaf(s, w.x, a.x); a.y = fmaf(s, w.y, a.y);
    a.z = fmaf(s, w.z, a.z); a.w = fmaf(s, w.w, a.w);
}

__global__ __launch_bounds__(256) void k_gemm1(const uint4* __restrict__ Xh,
                                               const float* __restrict__ W,
                                               const float* __restrict__ bias,
                                               __half2* __restrict__ Oh) {
    __shared__ float sW[DD * DD];
    int tid = threadIdx.x;
    for (int i = tid; i < DD * DD / 4; i += 256)
        ((float4*)sW)[i] = ((const float4*)W)[i];
    __syncthreads();
    int cg = tid & 7, s = tid >> 3;
    int base = blockIdx.x * 128;
    const float4* bv = (const float4*)bias + cg * 3;
    const uint4* xr0; const uint4* xr1; const uint4* xr2; const uint4* xr3;
    {
        int r0 = base + s;        int c0 = r0 < NN ? r0 : NN - 1;
        int r1 = base + s + 32;   int c1 = r1 < NN ? r1 : NN - 1;
        int r2 = base + s + 64;   int c2 = r2 < NN ? r2 : NN - 1;
        int r3 = base + s + 96;   int c3 = r3 < NN ? r3 : NN - 1;
        xr0 = Xh + (size_t)c0 * NH; xr1 = Xh + (size_t)c1 * NH;
        xr2 = Xh + (size_t)c2 * NH; xr3 = Xh + (size_t)c3 * NH;
    }
    float4 acc[4][3];
    #pragma unroll
    for (int j = 0; j < 4; ++j) { acc[j][0] = bv[0]; acc[j][1] = bv[1]; acc[j][2] = bv[2]; }

    #pragma unroll 2
    for (int k12 = 0; k12 < NH; ++k12) {
        float f0[8], f1[8], f2[8], f3[8];
        cvt8(xr0[k12], f0); cvt8(xr1[k12], f1); cvt8(xr2[k12], f2); cvt8(xr3[k12], f3);
        #pragma unroll
        for (int kk = 0; kk < 8; ++kk) {
            const float4* wr = (const float4*)&sW[(k12 * 8 + kk) * DD + cg * 12];
            float4 w0 = wr[0], w1 = wr[1], w2 = wr[2];
            fma4(acc[0][0], f0[kk], w0); fma4(acc[0][1], f0[kk], w1); fma4(acc[0][2], f0[kk], w2);
            fma4(acc[1][0], f1[kk], w0); fma4(acc[1][1], f1[kk], w1); fma4(acc[1][2], f1[kk], w2);
            fma4(acc[2][0], f2[kk], w0); fma4(acc[2][1], f2[kk], w1); fma4(acc[2][2], f2[kk], w2);
            fma4(acc[3][0], f3[kk], w0); fma4(acc[3][1], f3[kk], w1); fma4(acc[3][2], f3[kk], w2);
        }
    }
    #pragma unroll
    for (int j = 0; j < 4; ++j) {
        int row = base + s + 32 * j;
        if (row >= NN) continue;
        float4 a0 = acc[j][0], a1 = acc[j][1], a2 = acc[j][2];
        a0.x = fmaxf(a0.x, 0.f); a0.y = fmaxf(a0.y, 0.f); a0.z = fmaxf(a0.z, 0.f); a0.w = fmaxf(a0.w, 0.f);
        a1.x = fmaxf(a1.x, 0.f); a1.y = fmaxf(a1.y, 0.f); a1.z = fmaxf(a1.z, 0.f); a1.w = fmaxf(a1.w, 0.f);
        a2.x = fmaxf(a2.x, 0.f); a2.y = fmaxf(a2.y, 0.f); a2.z = fmaxf(a2.z, 0.f); a2.w = fmaxf(a2.w, 0.f);
        __half2* o = Oh + ((size_t)row * DD + cg * 12) / 2;
        o[0] = __floats2half2_rn(a0.x, a0.y);
        o[1] = __floats2half2_rn(a0.z, a0.w);
        o[2] = __floats2half2_rn(a1.x, a1.y);
        o[3] = __floats2half2_rn(a1.z, a1.w);
        o[4] = __floats2half2_rn(a2.x, a2.y);
        o[5] = __floats2half2_rn(a2.z, a2.w);
    }
}

// ---------------- tail: gemm2 (embed) + pool stage A in ONE dispatch ----------------
// blocks [0, NBG): embed = Ph @ W3 + b3 (f32 out). blocks [NBG, NBG+512): pool partials.
// Both consume Ph only; independent. Uniform branch per block.

__global__ __launch_bounds__(384) void k_tail(const uint4* __restrict__ Ph,
                                              const float* __restrict__ W3,
                                              const float* __restrict__ b3,
                                              float* __restrict__ embed,
                                              const int* __restrict__ batch,
                                              float* __restrict__ gsum) {
    int tid = threadIdx.x;
    if (blockIdx.x < NBG) {
        __shared__ float sW[DD * DD];
        for (int i = tid; i < DD * DD / 4; i += 384)
            ((float4*)sW)[i] = ((const float4*)W3)[i];
        __syncthreads();
        if (tid >= 256) return;
        int cg = tid & 7, s = tid >> 3;
        int base = blockIdx.x * 128;
        const float4* bv = (const float4*)b3 + cg * 3;
        const uint4* xr0; const uint4* xr1; const uint4* xr2; const uint4* xr3;
        {
            int r0 = base + s;        int c0 = r0 < NN ? r0 : NN - 1;
            int r1 = base + s + 32;   int c1 = r1 < NN ? r1 : NN - 1;
            int r2 = base + s + 64;   int c2 = r2 < NN ? r2 : NN - 1;
            int r3 = base + s + 96;   int c3 = r3 < NN ? r3 : NN - 1;
            xr0 = Ph + (size_t)c0 * NH; xr1 = Ph + (size_t)c1 * NH;
            xr2 = Ph + (size_t)c2 * NH; xr3 = Ph + (size_t)c3 * NH;
        }
        float4 acc[4][3];
        #pragma unroll
        for (int j = 0; j < 4; ++j) { acc[j][0] = bv[0]; acc[j][1] = bv[1]; acc[j][2] = bv[2]; }
        #pragma unroll 2
        for (int k12 = 0; k12 < NH; ++k12) {
            float f0[8], f1[8], f2[8], f3[8];
            cvt8(xr0[k12], f0); cvt8(xr1[k12], f1); cvt8(xr2[k12], f2); cvt8(xr3[k12], f3);
            #pragma unroll
            for (int kk = 0; kk < 8; ++kk) {
                const float4* wr = (const float4*)&sW[(k12 * 8 + kk) * DD + cg * 12];
                float4 w0 = wr[0], w1 = wr[1], w2 = wr[2];
                fma4(acc[0][0], f0[kk], w0); fma4(acc[0][1], f0[kk], w1); fma4(acc[0][2], f0[kk], w2);
                fma4(acc[1][0], f1[kk], w0); fma4(acc[1][1], f1[kk], w1); fma4(acc[1][2], f1[kk], w2);
                fma4(acc[2][0], f2[kk], w0); fma4(acc[2][1], f2[kk], w1); fma4(acc[2][2], f2[kk], w2);
                fma4(acc[3][0], f3[kk], w0); fma4(acc[3][1], f3[kk], w1); fma4(acc[3][2], f3[kk], w2);
            }
        }
        #pragma unroll
        for (int j = 0; j < 4; ++j) {
            int row = base + s + 32 * j;
            if (row >= NN) continue;
            float4* o = (float4*)(embed + (size_t)row * DD + cg * 12);
            o[0] = acc[j][0]; o[1] = acc[j][1]; o[2] = acc[j][2];
        }
    } else {
        // pool stage A
        const __half* P2 = (const __half*)Ph;
        int b = blockIdx.x - NBG;
        int g = b >> 3, s = b & 7;
        int d = tid % 96, t = tid / 96;
        int lo = 0, hi = NN;
        while (lo < hi) { int m = (lo + hi) >> 1; if (batch[m] < g) lo = m + 1; else hi = m; }
        int start = lo;
        lo = 0; hi = NN;
        while (lo < hi) { int m = (lo + hi) >> 1; if (batch[m] < g + 1) lo = m + 1; else hi = m; }
        int end = lo;
        float acc = 0.f;
        for (int i = start + s * 4 + t; i < end; i += 32)
            acc += __half2float(P2[(size_t)i * DD + d]);
        __shared__ float red[384];
        red[tid] = acc;
        __syncthreads();
        if (tid < 96) {
            float v = red[tid] + red[tid + 96] + red[tid + 192] + red[tid + 288];
            atomicAdd(&gsum[g * 96 + tid], v);
        }
    }
}

// ---------------- pool stage B: outG = gsum @ W4 + cnt * b4 ----------------

__global__ __launch_bounds__(96) void k_pool_b(const float* __restrict__ gsum,
                                               const int* __restrict__ batch,
                                               const float* __restrict__ W4,
                                               const float* __restrict__ b4,
                                               float* __restrict__ outG) {
    int g = blockIdx.x, d = threadIdx.x;
    __shared__ float srow[96];
    srow[d] = gsum[g * 96 + d];
    int lo = 0, hi = NN;
    while (lo < hi) { int m = (lo + hi) >> 1; if (batch[m] < g) lo = m + 1; else hi = m; }
    int start = lo;
    lo = 0; hi = NN;
    while (lo < hi) { int m = (lo + hi) >> 1; if (batch[m] < g + 1) lo = m + 1; else hi = m; }
    int end = lo;
    __syncthreads();
    float o = (float)(end - start) * b4[d];
    #pragma unroll 8
    for (int k = 0; k < 96; ++k) o = fmaf(srow[k], W4[k * 96 + d], o);
    outG[g * 96 + d] = o;
}

// ---------------- launch ----------------

extern "C" void kernel_launch(void* const* d_in, const int* in_sizes, int n_in,
                              void* d_out, int out_size, void* d_ws, size_t ws_size,
                              hipStream_t stream) {
    const float* x  = (const float*)d_in[0];
    const float* W1 = (const float*)d_in[1];
    const float* b1 = (const float*)d_in[2];
    const float* W3 = (const float*)d_in[3];
    const float* b3 = (const float*)d_in[4];
    const float* W4 = (const float*)d_in[5];
    const float* b4 = (const float*)d_in[6];
    const float* ew = (const float*)d_in[7];
    const int* ei   = (const int*)d_in[8];
    const int* src  = ei;
    const int* dst  = ei + EE;
    const int* batch = (const int*)d_in[9];

    float* out_embed = (float*)d_out;
    float* out_graph = out_embed + (size_t)NN * DD;

    char* w = (char*)d_ws;
    auto alloc = [&](size_t bytes) { char* p = w; w += (bytes + 255) & ~(size_t)255; return p; };
    u64* histo     = (u64*)  alloc((size_t)NCPY * NN * 8);
    unsigned* rank = (unsigned*)alloc((size_t)EE * 4);
    float* dinv    = (float*)alloc((size_t)NN * 4);
    int*   cnts    = (int*)  alloc((size_t)NN * 4);
    unsigned* xoff = (unsigned*)alloc((size_t)NN * NCPY * 4);
    int*   row_ptr = (int*)  alloc((size_t)(NN + 1) * 4);
    int*   bsums   = (int*)  alloc(256 * 4);
    float* gsum    = (float*)alloc((size_t)GG * DD * 4);
    int2*  csr     = (int2*) alloc((size_t)EE * 8);
    uint4* xh      = (uint4*)alloc((size_t)NN * DD * 2);   // fp16 x
    uint4* hh      = (uint4*)alloc((size_t)NN * DD * 2);   // fp16 h
    uint4* ph      = (uint4*)alloc((size_t)NN * DD * 2);   // fp16 P1, reused as P2

    int nbN = (NN + 255) / 256;       // 196
    int nbE = (EE + 255) / 256;       // 3125
    int nbP = (NN * DD / 8 + 255) / 256;

    k_pre<<<nbP, 256, 0, stream>>>(histo, gsum, (const float4*)x, xh);
    k_hist<<<nbE, 256, 0, stream>>>(dst, ew, histo, rank);
    k_dinv_reduce<<<nbN, 256, 0, stream>>>(histo, dinv, cnts, xoff, bsums);
    k_scan2<<<nbN, 256, 0, stream>>>(cnts, bsums, nbN, row_ptr);
    k_scatter<<<nbE, 256, 0, stream>>>(src, dst, ew, dinv, row_ptr, xoff, rank, csr);

    // P1 = A_hat @ x [fp16] ; h = relu(P1 @ W1 + b1) [fp16]
    k_prop_h<<<NN / 16, 192, 0, stream>>>(xh, csr, row_ptr, dinv, ph);
    k_gemm1<<<(NN + 127) / 128, 256, 0, stream>>>(ph, W1, b1, (__half2*)hh);
    // P2 = A_hat @ h [fp16] ; {embed = P2 @ W3 + b3} ∥ {pool partials}
    k_prop_h<<<NN / 16, 192, 0, stream>>>(hh, csr, row_ptr, dinv, ph);
    k_tail<<<NBG + GG * 8, 384, 0, stream>>>(ph, W3, b3, out_embed, batch, gsum);
    k_pool_b<<<GG, 96, 0, stream>>>(gsum, batch, W4, b4, out_graph);
}

// Round 11
// 211.617 us; speedup vs baseline: 2.0307x; 1.0024x over previous
//
#include <hip/hip_runtime.h>
#include <hip/hip_fp16.h>

#define NN 50000
#define EE 800000
#define DD 96
#define GG 64
#define NH 12    // uint4 (8-half) chunks per 96-half row
#define NHP 13   // padded LDS row stride in uint4 (conflict-free)

#define FPSCALE 16777216.0f           // 2^24 fixed-point for weight sums
#define MASK44 ((1ULL << 44) - 1)
#define NCPY 8   // histogram copies
#define NBG2 ((NN + 63) / 64)         // 782 gemm blocks (64-row tiles)

typedef unsigned long long u64;

__device__ __forceinline__ uint4 pack8(const float* f) {
    __half2 h0 = __floats2half2_rn(f[0], f[1]);
    __half2 h1 = __floats2half2_rn(f[2], f[3]);
    __half2 h2 = __floats2half2_rn(f[4], f[5]);
    __half2 h3 = __floats2half2_rn(f[6], f[7]);
    uint4 o;
    o.x = *(unsigned int*)&h0; o.y = *(unsigned int*)&h1;
    o.z = *(unsigned int*)&h2; o.w = *(unsigned int*)&h3;
    return o;
}

__device__ __forceinline__ void cvt8(uint4 v, float* f) {
    const __half2* h = (const __half2*)&v;
    #pragma unroll
    for (int k = 0; k < 4; ++k) {
        float2 t = __half22float2(h[k]);
        f[2 * k] = t.x; f[2 * k + 1] = t.y;
    }
}

__device__ __forceinline__ void fma4(float4& a, float s, const float4 w) {
    a.x = fmaf(s, w.x, a.x); a.y = fmaf(s, w.y, a.y);
    a.z = fmaf(s, w.z, a.z); a.w = fmaf(s, w.w, a.w);
}

// ---------------- pre-pass: zero state + x -> fp16 ----------------

__global__ void k_pre(u64* histo, float* gsum,
                      const float4* __restrict__ x, uint4* __restrict__ xh) {
    int i = blockIdx.x * 256 + threadIdx.x;
    if (i < NCPY * NN) histo[i] = 0ULL;
    if (i < GG * DD) gsum[i] = 0.f;
    if (i < NN * DD / 8) {
        float4 f0 = x[2 * i], f1 = x[2 * i + 1];
        float f[8] = {f0.x, f0.y, f0.z, f0.w, f1.x, f1.y, f1.z, f1.w};
        xh[i] = pack8(f);
    }
}

// ---------------- histogram: 1 u64 atomic per edge, 8 copies ----------------

__global__ void k_hist(const int* __restrict__ dst, const float* __restrict__ ew,
                       u64* histo, unsigned int* rank) {
    int e = blockIdx.x * 256 + threadIdx.x;
    int cpy = blockIdx.x & (NCPY - 1);
    if (e < EE) {
        u64 q = (u64)(ew[e] * FPSCALE + 0.5f);
        u64 old = atomicAdd(&histo[(size_t)cpy * NN + dst[e]], (1ULL << 44) | q);
        rank[e] = ((unsigned)cpy << 24) | (unsigned)(old >> 44);
    }
}

// ---------------- reduce 8 copies: dinv, per-copy offsets, block count sums ----------------

__global__ __launch_bounds__(256) void k_dinv_reduce(const u64* __restrict__ histo,
                                                     float* dinv, int* cnts,
                                                     unsigned* xoff, int* bsums) {
    __shared__ int s[256];
    int tid = threadIdx.x;
    int i = blockIdx.x * 256 + tid;
    int tot = 0;
    if (i < NN) {
        u64 wsum44 = 0;
        unsigned pre = 0;
        #pragma unroll
        for (int x = 0; x < NCPY; ++x) {
            u64 h = histo[(size_t)x * NN + i];
            wsum44 += h & MASK44;
            xoff[(size_t)i * NCPY + x] = pre;
            pre += (unsigned)(h >> 44);
        }
        tot = (int)pre;
        cnts[i] = tot;
        dinv[i] = rsqrtf(1.0f + (float)wsum44 * (1.0f / FPSCALE));
    }
    s[tid] = tot;
    __syncthreads();
    for (int off = 128; off > 0; off >>= 1) {
        if (tid < off) s[tid] += s[tid + off];
        __syncthreads();
    }
    if (tid == 0) bsums[blockIdx.x] = s[0];
}

// ---------------- merged scan ----------------

__global__ __launch_bounds__(256) void k_scan2(const int* __restrict__ cnts,
                                               const int* __restrict__ bsums,
                                               int nb, int* row_ptr) {
    __shared__ int s[256];
    int tid = threadIdx.x;
    int bv = (tid < nb) ? bsums[tid] : 0;
    s[tid] = bv; __syncthreads();
    for (int off = 1; off < 256; off <<= 1) {
        int t = (tid >= off) ? s[tid - off] : 0;
        __syncthreads();
        s[tid] += t;
        __syncthreads();
    }
    int pb = (blockIdx.x > 0) ? s[blockIdx.x - 1] : 0;
    __syncthreads();
    int i = blockIdx.x * 256 + tid;
    int v = (i < NN) ? cnts[i] : 0;
    s[tid] = v; __syncthreads();
    for (int off = 1; off < 256; off <<= 1) {
        int t = (tid >= off) ? s[tid - off] : 0;
        __syncthreads();
        s[tid] += t;
        __syncthreads();
    }
    if (i < NN) row_ptr[i] = pb + s[tid] - v;
    if (blockIdx.x == gridDim.x - 1 && tid == 255) row_ptr[NN] = EE;
}

// ---------------- scatter (no atomics) ----------------

__global__ void k_scatter(const int* __restrict__ src, const int* __restrict__ dst,
                          const float* __restrict__ ew, const float* __restrict__ dinv,
                          const int* __restrict__ row_ptr, const unsigned* __restrict__ xoff,
                          const unsigned int* __restrict__ rank, int2* csr) {
    int e = blockIdx.x * 256 + threadIdx.x;
    if (e < EE) {
        int s = src[e], d = dst[e];
        unsigned r = rank[e];
        int x = (int)(r >> 24);
        int p = row_ptr[d] + (int)xoff[(size_t)d * NCPY + x] + (int)(r & 0xFFFFFFu);
        float w = dinv[s] * ew[e] * dinv[d];
        csr[p] = make_int2(s, __float_as_int(w));
    }
}

// ---------------- propagation (CSR gather, fp16 in AND out) ----------------

__global__ __launch_bounds__(192) void k_prop_h(const uint4* __restrict__ Th,
                                                const int2* __restrict__ csr,
                                                const int* __restrict__ row_ptr,
                                                const float* __restrict__ dinv,
                                                uint4* __restrict__ Ph) {
    int tid = threadIdx.x;
    int node = blockIdx.x * 16 + tid / 12;
    int c = tid % 12;
    float di = dinv[node];
    float self = di * di;
    float f[8], acc[8];
    cvt8(Th[node * NH + c], f);
    #pragma unroll
    for (int j = 0; j < 8; ++j) acc[j] = self * f[j];
    int e0 = row_ptr[node], e1 = row_ptr[node + 1];
    for (int e = e0; e < e1; ++e) {
        int2 sw = csr[e];
        float w = __int_as_float(sw.y);
        cvt8(Th[sw.x * NH + c], f);
        #pragma unroll
        for (int j = 0; j < 8; ++j) acc[j] = fmaf(w, f[j], acc[j]);
    }
    Ph[node * NH + c] = pack8(acc);
}

// ---------------- GEMM layer 1: hh = relu(Xh @ W1 + b1), fp16 out ----------------
// 64-row tile staged in LDS (fp16, padded stride) + W f32 in LDS.
// 256 threads = 32 s x 8 cg; 2 rows/thread (s, s+32); each A row fetched ONCE.

__global__ __launch_bounds__(256) void k_gemm1(const uint4* __restrict__ Xh,
                                               const float* __restrict__ W,
                                               const float* __restrict__ bias,
                                               __half2* __restrict__ Oh) {
    __shared__ float sW[DD * DD];      // 36 KB
    __shared__ uint4 sA[64 * NHP];     // 13 KB
    int tid = threadIdx.x;
    int base = blockIdx.x * 64;
    for (int i = tid; i < DD * DD / 4; i += 256)
        ((float4*)sW)[i] = ((const float4*)W)[i];
    for (int i = tid; i < 64 * NH; i += 256) {
        int r = base + i / NH; r = r < NN ? r : NN - 1;
        sA[(i / NH) * NHP + (i % NH)] = Xh[(size_t)r * NH + (i % NH)];
    }
    __syncthreads();
    int s = tid >> 3, cg = tid & 7;
    const float4* bv = (const float4*)bias + cg * 3;
    float4 acc[2][3];
    #pragma unroll
    for (int j = 0; j < 2; ++j) { acc[j][0] = bv[0]; acc[j][1] = bv[1]; acc[j][2] = bv[2]; }

    #pragma unroll 3
    for (int k12 = 0; k12 < NH; ++k12) {
        float f0[8], f1[8];
        cvt8(sA[s * NHP + k12], f0);
        cvt8(sA[(s + 32) * NHP + k12], f1);
        #pragma unroll
        for (int kk = 0; kk < 8; ++kk) {
            const float4* wr = (const float4*)&sW[(k12 * 8 + kk) * DD + cg * 12];
            float4 w0 = wr[0], w1 = wr[1], w2 = wr[2];
            fma4(acc[0][0], f0[kk], w0); fma4(acc[0][1], f0[kk], w1); fma4(acc[0][2], f0[kk], w2);
            fma4(acc[1][0], f1[kk], w0); fma4(acc[1][1], f1[kk], w1); fma4(acc[1][2], f1[kk], w2);
        }
    }
    #pragma unroll
    for (int j = 0; j < 2; ++j) {
        int row = base + s + 32 * j;
        if (row >= NN) continue;
        float4 a0 = acc[j][0], a1 = acc[j][1], a2 = acc[j][2];
        a0.x = fmaxf(a0.x, 0.f); a0.y = fmaxf(a0.y, 0.f); a0.z = fmaxf(a0.z, 0.f); a0.w = fmaxf(a0.w, 0.f);
        a1.x = fmaxf(a1.x, 0.f); a1.y = fmaxf(a1.y, 0.f); a1.z = fmaxf(a1.z, 0.f); a1.w = fmaxf(a1.w, 0.f);
        a2.x = fmaxf(a2.x, 0.f); a2.y = fmaxf(a2.y, 0.f); a2.z = fmaxf(a2.z, 0.f); a2.w = fmaxf(a2.w, 0.f);
        __half2* o = Oh + ((size_t)row * DD + cg * 12) / 2;
        o[0] = __floats2half2_rn(a0.x, a0.y);
        o[1] = __floats2half2_rn(a0.z, a0.w);
        o[2] = __floats2half2_rn(a1.x, a1.y);
        o[3] = __floats2half2_rn(a1.z, a1.w);
        o[4] = __floats2half2_rn(a2.x, a2.y);
        o[5] = __floats2half2_rn(a2.z, a2.w);
    }
}

// ---------------- tail: gemm2 (embed, f32) + pool stage A in ONE dispatch ----------------
// blocks [0, NBG2): 64-row LDS-staged gemm. blocks [NBG2, NBG2+512): pool partials.

__global__ __launch_bounds__(384) void k_tail(const uint4* __restrict__ Ph,
                                              const float* __restrict__ W3,
                                              const float* __restrict__ b3,
                                              float* __restrict__ embed,
                                              const int* __restrict__ batch,
                                              float* __restrict__ gsum) {
    int tid = threadIdx.x;
    if (blockIdx.x < NBG2) {
        __shared__ float sW[DD * DD];
        __shared__ uint4 sA[64 * NHP];
        int base = blockIdx.x * 64;
        for (int i = tid; i < DD * DD / 4; i += 384)
            ((float4*)sW)[i] = ((const float4*)W3)[i];
        for (int i = tid; i < 64 * NH; i += 384) {
            int r = base + i / NH; r = r < NN ? r : NN - 1;
            sA[(i / NH) * NHP + (i % NH)] = Ph[(size_t)r * NH + (i % NH)];
        }
        __syncthreads();
        if (tid >= 256) return;
        int s = tid >> 3, cg = tid & 7;
        const float4* bv = (const float4*)b3 + cg * 3;
        float4 acc[2][3];
        #pragma unroll
        for (int j = 0; j < 2; ++j) { acc[j][0] = bv[0]; acc[j][1] = bv[1]; acc[j][2] = bv[2]; }
        #pragma unroll 3
        for (int k12 = 0; k12 < NH; ++k12) {
            float f0[8], f1[8];
            cvt8(sA[s * NHP + k12], f0);
            cvt8(sA[(s + 32) * NHP + k12], f1);
            #pragma unroll
            for (int kk = 0; kk < 8; ++kk) {
                const float4* wr = (const float4*)&sW[(k12 * 8 + kk) * DD + cg * 12];
                float4 w0 = wr[0], w1 = wr[1], w2 = wr[2];
                fma4(acc[0][0], f0[kk], w0); fma4(acc[0][1], f0[kk], w1); fma4(acc[0][2], f0[kk], w2);
                fma4(acc[1][0], f1[kk], w0); fma4(acc[1][1], f1[kk], w1); fma4(acc[1][2], f1[kk], w2);
            }
        }
        #pragma unroll
        for (int j = 0; j < 2; ++j) {
            int row = base + s + 32 * j;
            if (row >= NN) continue;
            float4* o = (float4*)(embed + (size_t)row * DD + cg * 12);
            o[0] = acc[j][0]; o[1] = acc[j][1]; o[2] = acc[j][2];
        }
    } else {
        const __half* P2 = (const __half*)Ph;
        int b = blockIdx.x - NBG2;
        int g = b >> 3, s = b & 7;
        int d = tid % 96, t = tid / 96;
        int lo = 0, hi = NN;
        while (lo < hi) { int m = (lo + hi) >> 1; if (batch[m] < g) lo = m + 1; else hi = m; }
        int start = lo;
        lo = 0; hi = NN;
        while (lo < hi) { int m = (lo + hi) >> 1; if (batch[m] < g + 1) lo = m + 1; else hi = m; }
        int end = lo;
        float acc = 0.f;
        for (int i = start + s * 4 + t; i < end; i += 32)
            acc += __half2float(P2[(size_t)i * DD + d]);
        __shared__ float red[384];
        red[tid] = acc;
        __syncthreads();
        if (tid < 96) {
            float v = red[tid] + red[tid + 96] + red[tid + 192] + red[tid + 288];
            atomicAdd(&gsum[g * 96 + tid], v);
        }
    }
}

// ---------------- pool stage B: outG = gsum @ W4 + cnt * b4 ----------------

__global__ __launch_bounds__(96) void k_pool_b(const float* __restrict__ gsum,
                                               const int* __restrict__ batch,
                                               const float* __restrict__ W4,
                                               const float* __restrict__ b4,
                                               float* __restrict__ outG) {
    int g = blockIdx.x, d = threadIdx.x;
    __shared__ float srow[96];
    srow[d] = gsum[g * 96 + d];
    int lo = 0, hi = NN;
    while (lo < hi) { int m = (lo + hi) >> 1; if (batch[m] < g) lo = m + 1; else hi = m; }
    int start = lo;
    lo = 0; hi = NN;
    while (lo < hi) { int m = (lo + hi) >> 1; if (batch[m] < g + 1) lo = m + 1; else hi = m; }
    int end = lo;
    __syncthreads();
    float o = (float)(end - start) * b4[d];
    #pragma unroll 8
    for (int k = 0; k < 96; ++k) o = fmaf(srow[k], W4[k * 96 + d], o);
    outG[g * 96 + d] = o;
}

// ---------------- launch ----------------

extern "C" void kernel_launch(void* const* d_in, const int* in_sizes, int n_in,
                              void* d_out, int out_size, void* d_ws, size_t ws_size,
                              hipStream_t stream) {
    const float* x  = (const float*)d_in[0];
    const float* W1 = (const float*)d_in[1];
    const float* b1 = (const float*)d_in[2];
    const float* W3 = (const float*)d_in[3];
    const float* b3 = (const float*)d_in[4];
    const float* W4 = (const float*)d_in[5];
    const float* b4 = (const float*)d_in[6];
    const float* ew = (const float*)d_in[7];
    const int* ei   = (const int*)d_in[8];
    const int* src  = ei;
    const int* dst  = ei + EE;
    const int* batch = (const int*)d_in[9];

    float* out_embed = (float*)d_out;
    float* out_graph = out_embed + (size_t)NN * DD;

    char* w = (char*)d_ws;
    auto alloc = [&](size_t bytes) { char* p = w; w += (bytes + 255) & ~(size_t)255; return p; };
    u64* histo     = (u64*)  alloc((size_t)NCPY * NN * 8);
    unsigned* rank = (unsigned*)alloc((size_t)EE * 4);
    float* dinv    = (float*)alloc((size_t)NN * 4);
    int*   cnts    = (int*)  alloc((size_t)NN * 4);
    unsigned* xoff = (unsigned*)alloc((size_t)NN * NCPY * 4);
    int*   row_ptr = (int*)  alloc((size_t)(NN + 1) * 4);
    int*   bsums   = (int*)  alloc(256 * 4);
    float* gsum    = (float*)alloc((size_t)GG * DD * 4);
    int2*  csr     = (int2*) alloc((size_t)EE * 8);
    uint4* xh      = (uint4*)alloc((size_t)NN * DD * 2);   // fp16 x
    uint4* hh      = (uint4*)alloc((size_t)NN * DD * 2);   // fp16 h
    uint4* ph      = (uint4*)alloc((size_t)NN * DD * 2);   // fp16 P1, reused as P2

    int nbN = (NN + 255) / 256;       // 196
    int nbE = (EE + 255) / 256;       // 3125
    int nbP = (NN * DD / 8 + 255) / 256;

    k_pre<<<nbP, 256, 0, stream>>>(histo, gsum, (const float4*)x, xh);
    k_hist<<<nbE, 256, 0, stream>>>(dst, ew, histo, rank);
    k_dinv_reduce<<<nbN, 256, 0, stream>>>(histo, dinv, cnts, xoff, bsums);
    k_scan2<<<nbN, 256, 0, stream>>>(cnts, bsums, nbN, row_ptr);
    k_scatter<<<nbE, 256, 0, stream>>>(src, dst, ew, dinv, row_ptr, xoff, rank, csr);

    // P1 = A_hat @ x [fp16] ; h = relu(P1 @ W1 + b1) [fp16]
    k_prop_h<<<NN / 16, 192, 0, stream>>>(xh, csr, row_ptr, dinv, ph);
    k_gemm1<<<NBG2, 256, 0, stream>>>(ph, W1, b1, (__half2*)hh);
    // P2 = A_hat @ h [fp16] ; {embed = P2 @ W3 + b3} ∥ {pool partials}
    k_prop_h<<<NN / 16, 192, 0, stream>>>(hh, csr, row_ptr, dinv, ph);
    k_tail<<<NBG2 + GG * 8, 384, 0, stream>>>(ph, W3, b3, out_embed, batch, gsum);
    k_pool_b<<<GG, 96, 0, stream>>>(gsum, batch, W4, b4, out_graph);
}